// Round 1
// 621.551 us; speedup vs baseline: 1.0105x; 1.0105x over previous
//
#include <hip/hip_runtime.h>
#include <hip/hip_fp16.h>
#include <stdint.h>

// Problem constants (B, S, H from the reference)
#define B_SZ 32
#define S_SZ 2048
#define H_SZ 1024
#define M_SZ (B_SZ * S_SZ)   // 65536 rows of the big GEMM

typedef _Float16 half8 __attribute__((ext_vector_type(8)));
typedef float floatx4 __attribute__((ext_vector_type(4)));

struct h4 { _Float16 x, y, z, w; };   // 8-byte packed fp16x4

// ---------------- fp32 -> fp16 convert (Wk only; enc conversion is fused) ----------------
__global__ __launch_bounds__(256) void convert_f32_to_f16(
    const float* __restrict__ in, h4* __restrict__ out, int n4) {
  int i = blockIdx.x * blockDim.x + threadIdx.x;
  int stride = gridDim.x * blockDim.x;
  const float4* in4 = (const float4*)in;
  for (; i < n4; i += stride) {
    float4 f = in4[i];
    h4 o;
    o.x = (_Float16)f.x; o.y = (_Float16)f.y;
    o.z = (_Float16)f.z; o.w = (_Float16)f.w;
    out[i] = o;
  }
}

// ---------------- query = hidden @ Wq^T  (fp32 exact, tiny) ----------------
__global__ __launch_bounds__(256) void query_kernel(
    const float* __restrict__ hidden, const float* __restrict__ Wq,
    float* __restrict__ q) {
  int t = blockIdx.x * blockDim.x + threadIdx.x;   // 32768 threads
  int b = t & 31;
  int n = t >> 5;
  const float4* h4p = (const float4*)(hidden + (size_t)b * H_SZ);
  const float4* w4p = (const float4*)(Wq + (size_t)n * H_SZ);
  float acc = 0.f;
  #pragma unroll 4
  for (int i = 0; i < H_SZ / 4; ++i) {
    float4 h = h4p[i], w = w4p[i];
    acc = fmaf(h.x, w.x, acc);
    acc = fmaf(h.y, w.y, acc);
    acc = fmaf(h.z, w.z, acc);
    acc = fmaf(h.w, w.w, acc);
  }
  q[(size_t)b * H_SZ + n] = acc;
}

// ---------------- async global->LDS, 16B per lane (per-lane SOURCE address) ----------------
__device__ __forceinline__ void gl_lds16(const void* g, void* l) {
  __builtin_amdgcn_global_load_lds(
      (const __attribute__((address_space(1))) void*)g,
      (__attribute__((address_space(3))) void*)l,
      16, 0, 0);
}

__device__ __forceinline__ float fast_tanh(float x) {
  float ax = fabsf(x);
  float e = __expf(ax * -2.0f);
  float t = (1.0f - e) / (1.0f + e);
  return copysignf(t, x);
}

// ---------------- fused fp32->fp16 + keys-GEMM + tanh + v-dot ----------------
// C[m,n] = sum_k A[m,k] * Bt[n,k]   (A = enc fp32 staged raw, Bt = Wk fp16)
// partial[bn][m] = sum_{n in col-tile} v[n]*tanh(q[b,n]+C[m,n])
//
// LDS chunk swizzle (bank-conflict fix, rule #21: swizzle BOTH source & read):
//   As fp32 [128][32]: 8x16B chunks/row, physical chunk p = c ^ ((row>>1)&7)
//   Bs fp16 [128][32]: 4x16B chunks/row, physical chunk p = c ^ ((row>>1)&3)
// global_load_lds dest stays linear; the XOR is applied to the per-lane
// global SOURCE address on the write side and to the ds_read address on
// the read side (same involution).
#define TILE 128
#define BK 32

__global__ __launch_bounds__(256) void fused_keys_kernel(
    const float* __restrict__ A,       // enc fp32, M_SZ x H_SZ
    const _Float16* __restrict__ Bt,   // Wk fp16, H_SZ x H_SZ
    const float* __restrict__ q,       // B_SZ x H_SZ (fp32)
    const float* __restrict__ v,       // H_SZ
    float* __restrict__ partial)       // 8 x M_SZ
{
  __shared__ __align__(16) float    As[TILE * BK];   // 16 KB fp32, chunk-swizzled
  __shared__ __align__(16) _Float16 Bs[TILE * BK];   //  8 KB fp16, chunk-swizzled
  __shared__ float rowsum[TILE];
  __shared__ float q_l[TILE];
  __shared__ float v_l[TILE];

  const int tid  = threadIdx.x;
  const int w    = tid >> 6;       // wave 0..3
  const int lane = tid & 63;

  // XCD-aware bijective swizzle: the 8 bn-blocks sharing one A row-tile all
  // land on the same XCD (hw%8 round-robin), so A is fetched into ONE L2.
  // nwg = 4096, 4096 % 8 == 0 -> simple form is bijective.
  const int hw   = blockIdx.x;
  const int xcd  = hw & 7;
  const int slot = hw >> 3;
  const int bn   = slot & 7;
  const int bm   = ((slot >> 3) << 3) | xcd;   // bm & 7 == xcd

  const int R0   = bm * TILE;         // global row base (b*S + s)
  const int C0   = bn * TILE;         // global col base (n dim of H)
  const int bidx = R0 >> 11;          // batch index; uniform (2048 % 128 == 0)

  if (tid < TILE) {
    q_l[tid] = q[(size_t)bidx * H_SZ + C0 + tid];
    v_l[tid] = v[C0 + tid];
    rowsum[tid] = 0.f;
  }

  const int wm = w >> 1, wn = w & 1;   // 2x2 wave grid, each wave 64x64
  const int cL = lane & 15, quad = lane >> 4;

  floatx4 acc[4][4];
  #pragma unroll
  for (int m = 0; m < 4; ++m)
    #pragma unroll
    for (int n = 0; n < 4; ++n)
      acc[m][n] = (floatx4){0.f, 0.f, 0.f, 0.f};

  // staging lane decomposition
  const int arow_l = lane >> 3;   // A: 8 lanes cover one 128B fp32 row-chunk set
  const int ap     = lane & 7;    //    physical 16B chunk 0..7
  const int brow_l = lane >> 2;   // B: 4 lanes cover one 64B fp16 row-chunk set
  const int bp     = lane & 3;    //    physical 16B chunk 0..3

  const float*    Ablk = A  + (size_t)R0 * H_SZ;
  const _Float16* Bblk = Bt + (size_t)C0 * H_SZ;

  for (int kt = 0; kt < H_SZ / BK; ++kt) {
    __syncthreads();               // previous tile's compute done before overwrite
    const int kof = kt * BK;
    // A fp32: 16 KB/step, 4 issues/wave; wave w owns rows [w*32, w*32+32)
    #pragma unroll
    for (int j = 0; j < 4; ++j) {
      const int row = w * 32 + j * 8 + arow_l;
      const int cg  = ap ^ ((row >> 1) & 7);           // pre-swizzled source chunk
      gl_lds16(Ablk + (size_t)row * H_SZ + kof + cg * 4,
               (char*)As + (w * 256 + j * 64) * 16);
    }
    // B fp16: 8 KB/step, 2 issues/wave
    #pragma unroll
    for (int j = 0; j < 2; ++j) {
      const int row = w * 32 + j * 16 + brow_l;
      const int cg  = bp ^ ((row >> 1) & 3);
      gl_lds16(Bblk + (size_t)row * H_SZ + kof + cg * 8,
               (char*)Bs + (w * 128 + j * 64) * 16);
    }
    __syncthreads();               // drain vmcnt + barrier (compiler handles)

    half8 af[4], bf[4];
    #pragma unroll
    for (int m = 0; m < 4; ++m) {
      const int r = wm * 64 + m * 16 + cL;
      const int s = (r >> 1) & 7;
      const float4* Af = (const float4*)As + r * 8;
      float4 f0 = Af[(2 * quad) ^ s];         // logical k = quad*8 .. +3
      float4 f1 = Af[(2 * quad + 1) ^ s];     // logical k = quad*8+4 .. +7
      af[m] = (half8){(_Float16)f0.x, (_Float16)f0.y, (_Float16)f0.z, (_Float16)f0.w,
                      (_Float16)f1.x, (_Float16)f1.y, (_Float16)f1.z, (_Float16)f1.w};
    }
    #pragma unroll
    for (int n = 0; n < 4; ++n) {
      const int r = wn * 64 + n * 16 + cL;
      const int s = (r >> 1) & 3;
      bf[n] = *(const half8*)(Bs + r * 32 + ((quad ^ s) << 3));
    }
    #pragma unroll
    for (int m = 0; m < 4; ++m)
      #pragma unroll
      for (int n = 0; n < 4; ++n)
        acc[m][n] = __builtin_amdgcn_mfma_f32_16x16x32_f16(af[m], bf[n], acc[m][n], 0, 0, 0);
  }

  // ---- epilogue: v[n]*tanh(q+c), reduce over this block's 128 columns ----
  float qv[4], vv[4];
  #pragma unroll
  for (int n = 0; n < 4; ++n) {
    const int col = wn * 64 + n * 16 + cL;
    qv[n] = q_l[col];
    vv[n] = v_l[col];
  }
  // C/D layout: col = lane&15, row = quad*4 + reg  [m89-verified, dtype-independent]
  #pragma unroll
  for (int m = 0; m < 4; ++m) {
    #pragma unroll
    for (int r = 0; r < 4; ++r) {
      float s = 0.f;
      #pragma unroll
      for (int n = 0; n < 4; ++n)
        s += vv[n] * fast_tanh(qv[n] + acc[m][n][r]);
      // reduce across the 16 lanes (cL) sharing this row
      s += __shfl_xor(s, 1);
      s += __shfl_xor(s, 2);
      s += __shfl_xor(s, 4);
      s += __shfl_xor(s, 8);
      if (cL == 0)
        atomicAdd(&rowsum[wm * 64 + m * 16 + quad * 4 + r], s);
    }
  }
  __syncthreads();
  if (tid < TILE)
    partial[(size_t)bn * M_SZ + R0 + tid] = rowsum[tid];
}

// ---------------- masked softmax over S per batch row ----------------
__global__ __launch_bounds__(256) void softmax_kernel(
    const float* __restrict__ partial, const int* __restrict__ lengths,
    float* __restrict__ out) {
  __shared__ float wred[4];
  __shared__ float wsum[4];
  const int b = blockIdx.x;
  const int tid = threadIdx.x;
  const int len = lengths[b];

  float lg[8];
  #pragma unroll
  for (int i = 0; i < 8; ++i) {
    const int s = tid + i * 256;
    const size_t row = (size_t)b * S_SZ + s;
    float l = 0.f;
    #pragma unroll
    for (int nt = 0; nt < 8; ++nt) l += partial[(size_t)nt * M_SZ + row];
    lg[i] = (s < len) ? l : -INFINITY;
  }

  float mx = lg[0];
  #pragma unroll
  for (int i = 1; i < 8; ++i) mx = fmaxf(mx, lg[i]);
  #pragma unroll
  for (int off = 32; off; off >>= 1) mx = fmaxf(mx, __shfl_xor(mx, off));
  if ((tid & 63) == 0) wred[tid >> 6] = mx;
  __syncthreads();
  mx = fmaxf(fmaxf(wred[0], wred[1]), fmaxf(wred[2], wred[3]));

  float pe[8];
  float sum = 0.f;
  #pragma unroll
  for (int i = 0; i < 8; ++i) {
    float e = (lg[i] == -INFINITY) ? 0.f : __expf(lg[i] - mx);
    pe[i] = e;
    sum += e;
  }
  #pragma unroll
  for (int off = 32; off; off >>= 1) sum += __shfl_xor(sum, off);
  if ((tid & 63) == 0) wsum[tid >> 6] = sum;
  __syncthreads();
  sum = wsum[0] + wsum[1] + wsum[2] + wsum[3];
  const float inv = 1.0f / sum;

  #pragma unroll
  for (int i = 0; i < 8; ++i) {
    const int s = tid + i * 256;
    out[(size_t)b * S_SZ + s] = pe[i] * inv;
  }
}

extern "C" void kernel_launch(void* const* d_in, const int* in_sizes, int n_in,
                              void* d_out, int out_size, void* d_ws, size_t ws_size,
                              hipStream_t stream) {
  const float* hidden  = (const float*)d_in[0];  // (32, 1024)
  const float* enc     = (const float*)d_in[1];  // (32, 2048, 1024)
  const int*   lengths = (const int*)d_in[2];    // (32,)
  const float* Wq      = (const float*)d_in[3];  // (1024, 1024)
  const float* Wk      = (const float*)d_in[4];  // (1024, 1024)
  const float* v       = (const float*)d_in[5];  // (1024,)
  float* out = (float*)d_out;                    // (32, 2048) fp32

  // ws layout: B16 (2 MB) | q (128 KB) | partial (2 MB)   — 4.2 MB total
  char* ws = (char*)d_ws;
  _Float16* B16     = (_Float16*)ws;
  float*    q       = (float*)(ws + 2097152);
  float*    partial = (float*)(ws + 2097152 + 131072);

  convert_f32_to_f16<<<1024, 256, 0, stream>>>(Wk, (h4*)B16, (H_SZ * H_SZ) / 4);
  query_kernel<<<128, 256, 0, stream>>>(hidden, Wq, q);
  fused_keys_kernel<<<(M_SZ / TILE) * (H_SZ / TILE), 256, 0, stream>>>(enc, B16, q, v, partial);
  softmax_kernel<<<B_SZ, 256, 0, stream>>>(partial, lengths, out);
}

// Round 3
// 620.596 us; speedup vs baseline: 1.0121x; 1.0015x over previous
//
#include <hip/hip_runtime.h>
#include <hip/hip_fp16.h>
#include <stdint.h>

// Problem constants (B, S, H from the reference)
#define B_SZ 32
#define S_SZ 2048
#define H_SZ 1024
#define M_SZ (B_SZ * S_SZ)   // 65536 rows of the big GEMM

typedef _Float16 half8 __attribute__((ext_vector_type(8)));
typedef float floatx4 __attribute__((ext_vector_type(4)));

struct h4 { _Float16 x, y, z, w; };   // 8-byte packed fp16x4

// ---------------- fp32 -> fp16 convert (Wk only; enc conversion is fused) ----------------
__global__ __launch_bounds__(256) void convert_f32_to_f16(
    const float* __restrict__ in, h4* __restrict__ out, int n4) {
  int i = blockIdx.x * blockDim.x + threadIdx.x;
  int stride = gridDim.x * blockDim.x;
  const float4* in4 = (const float4*)in;
  for (; i < n4; i += stride) {
    float4 f = in4[i];
    h4 o;
    o.x = (_Float16)f.x; o.y = (_Float16)f.y;
    o.z = (_Float16)f.z; o.w = (_Float16)f.w;
    out[i] = o;
  }
}

// ---------------- query = hidden @ Wq^T  (fp32 exact, tiny) ----------------
__global__ __launch_bounds__(256) void query_kernel(
    const float* __restrict__ hidden, const float* __restrict__ Wq,
    float* __restrict__ q) {
  int t = blockIdx.x * blockDim.x + threadIdx.x;   // 32768 threads
  int b = t & 31;
  int n = t >> 5;
  const float4* h4p = (const float4*)(hidden + (size_t)b * H_SZ);
  const float4* w4p = (const float4*)(Wq + (size_t)n * H_SZ);
  float acc = 0.f;
  #pragma unroll 4
  for (int i = 0; i < H_SZ / 4; ++i) {
    float4 h = h4p[i], w = w4p[i];
    acc = fmaf(h.x, w.x, acc);
    acc = fmaf(h.y, w.y, acc);
    acc = fmaf(h.z, w.z, acc);
    acc = fmaf(h.w, w.w, acc);
  }
  q[(size_t)b * H_SZ + n] = acc;
}

// ---------------- async global->LDS, 16B per lane (per-lane SOURCE address) ----------------
__device__ __forceinline__ void gl_lds16(const void* g, void* l) {
  __builtin_amdgcn_global_load_lds(
      (const __attribute__((address_space(1))) void*)g,
      (__attribute__((address_space(3))) void*)l,
      16, 0, 0);
}

__device__ __forceinline__ float fast_tanh(float x) {
  float ax = fabsf(x);
  float e = __expf(ax * -2.0f);
  float t = (1.0f - e) / (1.0f + e);
  return copysignf(t, x);
}

// ---------------- fused fp32->fp16 + keys-GEMM + tanh + v-dot ----------------
// C[m,n] = sum_k A[m,k] * Bt[n,k]   (A = enc fp32 staged raw, Bt = Wk fp16)
// partial[bn][m] = sum_{n in col-tile} v[n]*tanh(q[b,n]+C[m,n])
//
// Structure:
//  - 4x1 wave grid: wave w owns rows [w*32, w*32+32) x all 128 cols.
//    A elements converted f32->f16 ONCE per block, no epilogue atomics.
//  - Double-buffered LDS + single __syncthreads per K-step, STAGE issued
//    BEFORE compute so global_load_lds flies under ds_read+cvt+MFMA
//    (catalog minimum-2-phase; __syncthreads provides vmcnt(0)+barrier drain).
//  - LDS chunk swizzle (conflict-free per 16-lane phase):
//    As fp32 [128][32]: phys 16B chunk p = c ^ ((row>>1)&7)
//    Bs fp16 [128][32]: phys 16B chunk p = c ^ ((row>>1)&3)
//    applied on the per-lane global SOURCE (write) and ds_read addr (read).
#define TILE 128
#define BK 32

__global__ __launch_bounds__(256) void fused_keys_kernel(
    const float* __restrict__ A,       // enc fp32, M_SZ x H_SZ
    const _Float16* __restrict__ Bt,   // Wk fp16, H_SZ x H_SZ
    const float* __restrict__ q,       // B_SZ x H_SZ (fp32)
    const float* __restrict__ v,       // H_SZ
    float* __restrict__ partial)       // 8 x M_SZ
{
  __shared__ __align__(16) float    As[2][TILE * BK];   // 2 x 16 KB fp32
  __shared__ __align__(16) _Float16 Bs[2][TILE * BK];   // 2 x  8 KB fp16
  __shared__ float q_l[TILE];
  __shared__ float v_l[TILE];

  const int tid  = threadIdx.x;
  const int w    = tid >> 6;       // wave 0..3
  const int lane = tid & 63;

  // XCD-aware bijective swizzle: the 8 bn-blocks sharing one A row-tile all
  // land on the same XCD. nwg = 4096, 4096 % 8 == 0 -> bijective.
  const int hw   = blockIdx.x;
  const int xcd  = hw & 7;
  const int slot = hw >> 3;
  const int bn   = slot & 7;
  const int bm   = ((slot >> 3) << 3) | xcd;   // bm & 7 == xcd

  const int R0   = bm * TILE;         // global row base (b*S + s)
  const int C0   = bn * TILE;         // global col base (n dim of H)
  const int bidx = R0 >> 11;          // batch index; uniform (2048 % 128 == 0)

  if (tid < TILE) {
    q_l[tid] = q[(size_t)bidx * H_SZ + C0 + tid];
    v_l[tid] = v[C0 + tid];
  }

  const int cL   = lane & 15, quad = lane >> 4;
  const int sA   = cL >> 1;        // A-read swizzle key, 0..7
  const int sB   = sA & 3;         // B-read swizzle key, 0..3

  floatx4 acc[2][8];
  #pragma unroll
  for (int m = 0; m < 2; ++m)
    #pragma unroll
    for (int n = 0; n < 8; ++n)
      acc[m][n] = (floatx4){0.f, 0.f, 0.f, 0.f};

  // staging lane decomposition
  const int arow_l = lane >> 3;   // A: 8 lanes cover one 128B fp32 row
  const int ap     = lane & 7;    //    physical 16B chunk 0..7
  const int brow_l = lane >> 2;   // B: 4 lanes cover one 64B fp16 row
  const int bp     = lane & 3;    //    physical 16B chunk 0..3

  const float*    Ablk = A  + (size_t)R0 * H_SZ;
  const _Float16* Bblk = Bt + (size_t)C0 * H_SZ;

  // ---- stage tile kt2 into buffer b (issue only; no wait here) ----
  auto stage = [&](int kt2, int b) {
    const int kof = kt2 * BK;
    #pragma unroll
    for (int j = 0; j < 4; ++j) {
      const int row = w * 32 + j * 8 + arow_l;
      const int cg  = ap ^ ((row >> 1) & 7);           // pre-swizzled source chunk
      gl_lds16(Ablk + (size_t)row * H_SZ + kof + cg * 4,
               (char*)&As[b][0] + (w * 256 + j * 64) * 16);
    }
    #pragma unroll
    for (int j = 0; j < 2; ++j) {
      const int row = w * 32 + j * 16 + brow_l;
      const int cg  = bp ^ ((row >> 1) & 3);
      gl_lds16(Bblk + (size_t)row * H_SZ + kof + cg * 8,
               (char*)&Bs[b][0] + (w * 128 + j * 64) * 16);
    }
  };

  // ---- compute one K-step from buffer b, accumulate into acc ----
  auto compute = [&](int b) {
    half8 af[2], bf[8];
    #pragma unroll
    for (int m = 0; m < 2; ++m) {
      const int r = w * 32 + m * 16 + cL;
      const float4* Af = (const float4*)&As[b][0] + r * 8;
      float4 f0 = Af[(2 * quad) ^ sA];         // logical k = quad*8 .. +3
      float4 f1 = Af[(2 * quad + 1) ^ sA];     // logical k = quad*8+4 .. +7
      af[m] = (half8){(_Float16)f0.x, (_Float16)f0.y, (_Float16)f0.z, (_Float16)f0.w,
                      (_Float16)f1.x, (_Float16)f1.y, (_Float16)f1.z, (_Float16)f1.w};
    }
    #pragma unroll
    for (int n = 0; n < 8; ++n) {
      const int r = n * 16 + cL;
      bf[n] = *(const half8*)(&Bs[b][0] + r * 32 + ((quad ^ sB) << 3));
    }
    #pragma unroll
    for (int m = 0; m < 2; ++m)
      #pragma unroll
      for (int n = 0; n < 8; ++n)
        acc[m][n] = __builtin_amdgcn_mfma_f32_16x16x32_f16(af[m], bf[n], acc[m][n], 0, 0, 0);
  };

  // ---- main loop: stage(kt+1) overlaps compute(kt) ----
  stage(0, 0);
  __syncthreads();                 // vmcnt(0) drain + barrier: tile 0 ready
  int cur = 0;
  for (int kt = 0; kt < H_SZ / BK - 1; ++kt) {
    stage(kt + 1, cur ^ 1);        // in flight across the compute below
    compute(cur);
    __syncthreads();               // vmcnt(0)+lgkmcnt(0) drain + barrier
    cur ^= 1;
  }
  compute(cur);

  // ---- epilogue: v[n]*tanh(q+c), each wave owns its 32 rows ----
  float qv[8], vv[8];
  #pragma unroll
  for (int n = 0; n < 8; ++n) {
    const int col = n * 16 + cL;
    qv[n] = q_l[col];
    vv[n] = v_l[col];
  }
  // C/D layout: col = lane&15, row = quad*4 + reg  [m89-verified]
  #pragma unroll
  for (int m = 0; m < 2; ++m) {
    #pragma unroll
    for (int r = 0; r < 4; ++r) {
      float s = 0.f;
      #pragma unroll
      for (int n = 0; n < 8; ++n)
        s += vv[n] * fast_tanh(qv[n] + acc[m][n][r]);
      // reduce across the 16 lanes (cL) sharing this row
      s += __shfl_xor(s, 1);
      s += __shfl_xor(s, 2);
      s += __shfl_xor(s, 4);
      s += __shfl_xor(s, 8);
      if (cL == 0)
        partial[(size_t)bn * M_SZ + R0 + w * 32 + m * 16 + quad * 4 + r] = s;
    }
  }
}

// ---------------- masked softmax over S per batch row ----------------
__global__ __launch_bounds__(256) void softmax_kernel(
    const float* __restrict__ partial, const int* __restrict__ lengths,
    float* __restrict__ out) {
  __shared__ float wred[4];
  __shared__ float wsum[4];
  const int b = blockIdx.x;
  const int tid = threadIdx.x;
  const int len = lengths[b];

  float lg[8];
  #pragma unroll
  for (int i = 0; i < 8; ++i) {
    const int s = tid + i * 256;
    const size_t row = (size_t)b * S_SZ + s;
    float l = 0.f;
    #pragma unroll
    for (int nt = 0; nt < 8; ++nt) l += partial[(size_t)nt * M_SZ + row];
    lg[i] = (s < len) ? l : -INFINITY;
  }

  float mx = lg[0];
  #pragma unroll
  for (int i = 1; i < 8; ++i) mx = fmaxf(mx, lg[i]);
  #pragma unroll
  for (int off = 32; off; off >>= 1) mx = fmaxf(mx, __shfl_xor(mx, off));
  if ((tid & 63) == 0) wred[tid >> 6] = mx;
  __syncthreads();
  mx = fmaxf(fmaxf(wred[0], wred[1]), fmaxf(wred[2], wred[3]));

  float pe[8];
  float sum = 0.f;
  #pragma unroll
  for (int i = 0; i < 8; ++i) {
    float e = (lg[i] == -INFINITY) ? 0.f : __expf(lg[i] - mx);
    pe[i] = e;
    sum += e;
  }
  #pragma unroll
  for (int off = 32; off; off >>= 1) sum += __shfl_xor(sum, off);
  if ((tid & 63) == 0) wsum[tid >> 6] = sum;
  __syncthreads();
  sum = wsum[0] + wsum[1] + wsum[2] + wsum[3];
  const float inv = 1.0f / sum;

  #pragma unroll
  for (int i = 0; i < 8; ++i) {
    const int s = tid + i * 256;
    out[(size_t)b * S_SZ + s] = pe[i] * inv;
  }
}

extern "C" void kernel_launch(void* const* d_in, const int* in_sizes, int n_in,
                              void* d_out, int out_size, void* d_ws, size_t ws_size,
                              hipStream_t stream) {
  const float* hidden  = (const float*)d_in[0];  // (32, 1024)
  const float* enc     = (const float*)d_in[1];  // (32, 2048, 1024)
  const int*   lengths = (const int*)d_in[2];    // (32,)
  const float* Wq      = (const float*)d_in[3];  // (1024, 1024)
  const float* Wk      = (const float*)d_in[4];  // (1024, 1024)
  const float* v       = (const float*)d_in[5];  // (1024,)
  float* out = (float*)d_out;                    // (32, 2048) fp32

  // ws layout: B16 (2 MB) | q (128 KB) | partial (2 MB)   — 4.2 MB total
  char* ws = (char*)d_ws;
  _Float16* B16     = (_Float16*)ws;
  float*    q       = (float*)(ws + 2097152);
  float*    partial = (float*)(ws + 2097152 + 131072);

  convert_f32_to_f16<<<1024, 256, 0, stream>>>(Wk, (h4*)B16, (H_SZ * H_SZ) / 4);
  query_kernel<<<128, 256, 0, stream>>>(hidden, Wq, q);
  fused_keys_kernel<<<(M_SZ / TILE) * (H_SZ / TILE), 256, 0, stream>>>(enc, B16, q, v, partial);
  softmax_kernel<<<B_SZ, 256, 0, stream>>>(partial, lengths, out);
}

// Round 4
// 610.019 us; speedup vs baseline: 1.0296x; 1.0173x over previous
//
#include <hip/hip_runtime.h>
#include <hip/hip_fp16.h>
#include <stdint.h>

// Problem constants (B, S, H from the reference)
#define B_SZ 32
#define S_SZ 2048
#define H_SZ 1024
#define M_SZ (B_SZ * S_SZ)   // 65536 rows of the big GEMM

typedef _Float16 half8 __attribute__((ext_vector_type(8)));
typedef float floatx4 __attribute__((ext_vector_type(4)));

struct h4 { _Float16 x, y, z, w; };   // 8-byte packed fp16x4

// ---------------- fp32 -> fp16 convert (Wk only) ----------------
__global__ __launch_bounds__(256) void convert_f32_to_f16(
    const float* __restrict__ in, h4* __restrict__ out, int n4) {
  int i = blockIdx.x * blockDim.x + threadIdx.x;
  int stride = gridDim.x * blockDim.x;
  const float4* in4 = (const float4*)in;
  for (; i < n4; i += stride) {
    float4 f = in4[i];
    h4 o;
    o.x = (_Float16)f.x; o.y = (_Float16)f.y;
    o.z = (_Float16)f.z; o.w = (_Float16)f.w;
    out[i] = o;
  }
}

// ---------------- query = hidden @ Wq^T  (fp32 exact, tiny) ----------------
__global__ __launch_bounds__(256) void query_kernel(
    const float* __restrict__ hidden, const float* __restrict__ Wq,
    float* __restrict__ q) {
  int t = blockIdx.x * blockDim.x + threadIdx.x;   // 32768 threads
  int b = t & 31;
  int n = t >> 5;
  const float4* h4p = (const float4*)(hidden + (size_t)b * H_SZ);
  const float4* w4p = (const float4*)(Wq + (size_t)n * H_SZ);
  float acc = 0.f;
  #pragma unroll 4
  for (int i = 0; i < H_SZ / 4; ++i) {
    float4 h = h4p[i], w = w4p[i];
    acc = fmaf(h.x, w.x, acc);
    acc = fmaf(h.y, w.y, acc);
    acc = fmaf(h.z, w.z, acc);
    acc = fmaf(h.w, w.w, acc);
  }
  q[(size_t)b * H_SZ + n] = acc;
}

// ---------------- async global->LDS, 16B per lane (per-lane SOURCE address) ----------------
__device__ __forceinline__ void gl_lds16(const void* g, void* l) {
  __builtin_amdgcn_global_load_lds(
      (const __attribute__((address_space(1))) void*)g,
      (__attribute__((address_space(3))) void*)l,
      16, 0, 0);
}

__device__ __forceinline__ float fast_tanh(float x) {
  float ax = fabsf(x);
  float e = __expf(ax * -2.0f);
  float t = (1.0f - e) / (1.0f + e);
  return copysignf(t, x);
}

// ---------------- fused fp32->fp16 + keys-GEMM + tanh + v-dot ----------------
// C[m,n] = sum_k A[m,k] * Bt[n,k]
// partial[bn][m] = sum_{n in col-tile} v[n]*tanh(q[b,n]+C[m,n])
//
// Round-4 structure (occupancy attack):
//  - A is REG-STAGED: fp32 global -> regs -> RTE cvt fp16 -> swizzled ds_write.
//    As becomes fp16 (8 KB/buffer): LDS total 34 KB -> 4 blocks/CU (was 50 KB,
//    ~2.6 blocks/CU, 80% per-block stall undermasked).  __launch_bounds__(256,4)
//    caps VGPR at 128 so 16 waves/CU are schedulable.
//  - B stays on global_load_lds (proven faster for linear staging).
//  - Double buffer, ONE barrier per K-step: stage-issue at loop top is already
//    ordered against the previous compute by the previous iteration's barrier;
//    the end-of-step __syncthreads (vmcnt0+lgkm0 drain) publishes both stages.
//  - Both LDS tiles fp16 [128][32], 4x16B chunks/row, phys chunk p = c ^ ((row>>1)&3),
//    applied write-side (A: ds_write addr; B: pre-swizzled global source) and
//    read-side (same involution).  4x1 wave grid: wave w owns rows [w*32, w*32+32).
#define TILE 128
#define BK 32

__global__ __launch_bounds__(256, 4) void fused_keys_kernel(
    const float* __restrict__ A,       // enc fp32, M_SZ x H_SZ
    const _Float16* __restrict__ Bt,   // Wk fp16, H_SZ x H_SZ
    const float* __restrict__ q,       // B_SZ x H_SZ (fp32)
    const float* __restrict__ v,       // H_SZ
    float* __restrict__ partial)       // 8 x M_SZ
{
  __shared__ __align__(16) _Float16 As[2][TILE * BK];   // 2 x 8 KB fp16
  __shared__ __align__(16) _Float16 Bs[2][TILE * BK];   // 2 x 8 KB fp16
  __shared__ float q_l[TILE];
  __shared__ float v_l[TILE];

  const int tid  = threadIdx.x;
  const int w    = tid >> 6;       // wave 0..3
  const int lane = tid & 63;

  // XCD-aware bijective swizzle: the 8 bn-blocks sharing one A row-tile all
  // land on the same XCD. nwg = 4096, 4096 % 8 == 0 -> bijective.
  const int hw   = blockIdx.x;
  const int xcd  = hw & 7;
  const int slot = hw >> 3;
  const int bn   = slot & 7;
  const int bm   = ((slot >> 3) << 3) | xcd;   // bm & 7 == xcd

  const int R0   = bm * TILE;         // global row base (b*S + s)
  const int C0   = bn * TILE;         // global col base (n dim of H)
  const int bidx = R0 >> 11;          // batch index; uniform (2048 % 128 == 0)

  if (tid < TILE) {
    q_l[tid] = q[(size_t)bidx * H_SZ + C0 + tid];
    v_l[tid] = v[C0 + tid];
  }

  const int cL   = lane & 15, quad = lane >> 4;
  const int sB   = (cL >> 1) & 3;  // read swizzle key (same for A and B rows)

  floatx4 acc[2][8];
  #pragma unroll
  for (int m = 0; m < 2; ++m)
    #pragma unroll
    for (int n = 0; n < 8; ++n)
      acc[m][n] = (floatx4){0.f, 0.f, 0.f, 0.f};

  // ---- A reg-staging lane decomposition: 2 lanes per row, 16 floats each ----
  const int arow = w * 32 + (lane >> 1);  // row this lane stages
  const int ah   = lane & 1;              // which 16-float half of the 32-float row
  const int akey = (lane >> 2) & 3;       // == (arow>>1)&3
  const int ap0  = (2 * ah)     ^ akey;   // phys chunk for halves [16ah, 16ah+8)
  const int ap1  = (2 * ah + 1) ^ akey;   // phys chunk for halves [16ah+8, 16ah+16)
  const float* Asrc = A + (size_t)(R0 + arow) * H_SZ + ah * 16;

  // ---- B staging lane decomposition (global_load_lds, source-swizzled) ----
  const int brow_l = lane >> 2;   // 4 lanes cover one 64B fp16 row
  const int bp     = lane & 3;    // physical 16B chunk 0..3
  const _Float16* Bblk = Bt + (size_t)C0 * H_SZ;

  // ---- issue B global_load_lds for K-tile kt2 into buffer b ----
  auto stageB = [&](int kt2, int b) {
    const int kof = kt2 * BK;
    #pragma unroll
    for (int j = 0; j < 2; ++j) {
      const int row = w * 32 + j * 16 + brow_l;
      const int cg  = bp ^ ((row >> 1) & 3);
      gl_lds16(Bblk + (size_t)row * H_SZ + kof + cg * 8,
               (char*)&Bs[b][0] + (w * 128 + j * 64) * 16);
    }
  };

  // ---- load A fp32 for K-tile kt2 into regs (issue; compiler inserts waits) ----
  float4 ar[4];
  auto loadA = [&](int kt2) {
    const float4* p = (const float4*)(Asrc + kt2 * BK);
    ar[0] = p[0]; ar[1] = p[1]; ar[2] = p[2]; ar[3] = p[3];
  };

  // ---- cvt regs -> fp16, swizzled ds_write into As[b] ----
  auto writeA = [&](int b) {
    half8 h0 = (half8){(_Float16)ar[0].x, (_Float16)ar[0].y, (_Float16)ar[0].z, (_Float16)ar[0].w,
                       (_Float16)ar[1].x, (_Float16)ar[1].y, (_Float16)ar[1].z, (_Float16)ar[1].w};
    half8 h1 = (half8){(_Float16)ar[2].x, (_Float16)ar[2].y, (_Float16)ar[2].z, (_Float16)ar[2].w,
                       (_Float16)ar[3].x, (_Float16)ar[3].y, (_Float16)ar[3].z, (_Float16)ar[3].w};
    _Float16* dst = &As[b][arow * BK];
    *(half8*)(dst + ap0 * 8) = h0;
    *(half8*)(dst + ap1 * 8) = h1;
  };

  // ---- compute one K-step from buffer b ----
  auto compute = [&](int b) {
    half8 af[2], bf[8];
    #pragma unroll
    for (int m = 0; m < 2; ++m) {
      const int r = w * 32 + m * 16 + cL;
      af[m] = *(const half8*)(&As[b][r * BK] + ((quad ^ sB) << 3));
    }
    #pragma unroll
    for (int n = 0; n < 8; ++n) {
      const int r = n * 16 + cL;
      bf[n] = *(const half8*)(&Bs[b][r * BK] + ((quad ^ sB) << 3));
    }
    #pragma unroll
    for (int m = 0; m < 2; ++m)
      #pragma unroll
      for (int n = 0; n < 8; ++n)
        acc[m][n] = __builtin_amdgcn_mfma_f32_16x16x32_f16(af[m], bf[n], acc[m][n], 0, 0, 0);
  };

  // ---- prologue: stage tile 0 ----
  loadA(0);
  stageB(0, 0);
  writeA(0);
  __syncthreads();                 // drain vmcnt+lgkm: tile 0 ready (also covers q_l/v_l)

  // ---- main loop: stage(kt+1) overlaps compute(kt); ONE barrier per step ----
  int cur = 0;
  for (int kt = 0; kt < H_SZ / BK - 1; ++kt) {
    loadA(kt + 1);                 // fp32 -> regs, flies under compute
    stageB(kt + 1, cur ^ 1);       // DMA into Bs[nxt], flies under compute
    compute(cur);
    writeA(cur ^ 1);               // waits A-regs only (vmcnt counts B behind them)
    __syncthreads();               // vmcnt(0)+lgkmcnt(0)+barrier: tile kt+1 ready
    cur ^= 1;
  }
  compute(cur);

  // ---- epilogue: v[n]*tanh(q+c), each wave owns its 32 rows ----
  float qv[8], vv[8];
  #pragma unroll
  for (int n = 0; n < 8; ++n) {
    const int col = n * 16 + cL;
    qv[n] = q_l[col];
    vv[n] = v_l[col];
  }
  // C/D layout: col = lane&15, row = quad*4 + reg  [m89-verified]
  #pragma unroll
  for (int m = 0; m < 2; ++m) {
    #pragma unroll
    for (int r = 0; r < 4; ++r) {
      float s = 0.f;
      #pragma unroll
      for (int n = 0; n < 8; ++n)
        s += vv[n] * fast_tanh(qv[n] + acc[m][n][r]);
      // reduce across the 16 lanes (cL) sharing this row
      s += __shfl_xor(s, 1);
      s += __shfl_xor(s, 2);
      s += __shfl_xor(s, 4);
      s += __shfl_xor(s, 8);
      if (cL == 0)
        partial[(size_t)bn * M_SZ + R0 + w * 32 + m * 16 + quad * 4 + r] = s;
    }
  }
}

// ---------------- masked softmax over S per batch row ----------------
__global__ __launch_bounds__(256) void softmax_kernel(
    const float* __restrict__ partial, const int* __restrict__ lengths,
    float* __restrict__ out) {
  __shared__ float wred[4];
  __shared__ float wsum[4];
  const int b = blockIdx.x;
  const int tid = threadIdx.x;
  const int len = lengths[b];

  float lg[8];
  #pragma unroll
  for (int i = 0; i < 8; ++i) {
    const int s = tid + i * 256;
    const size_t row = (size_t)b * S_SZ + s;
    float l = 0.f;
    #pragma unroll
    for (int nt = 0; nt < 8; ++nt) l += partial[(size_t)nt * M_SZ + row];
    lg[i] = (s < len) ? l : -INFINITY;
  }

  float mx = lg[0];
  #pragma unroll
  for (int i = 1; i < 8; ++i) mx = fmaxf(mx, lg[i]);
  #pragma unroll
  for (int off = 32; off; off >>= 1) mx = fmaxf(mx, __shfl_xor(mx, off));
  if ((tid & 63) == 0) wred[tid >> 6] = mx;
  __syncthreads();
  mx = fmaxf(fmaxf(wred[0], wred[1]), fmaxf(wred[2], wred[3]));

  float pe[8];
  float sum = 0.f;
  #pragma unroll
  for (int i = 0; i < 8; ++i) {
    float e = (lg[i] == -INFINITY) ? 0.f : __expf(lg[i] - mx);
    pe[i] = e;
    sum += e;
  }
  #pragma unroll
  for (int off = 32; off; off >>= 1) sum += __shfl_xor(sum, off);
  if ((tid & 63) == 0) wsum[tid >> 6] = sum;
  __syncthreads();
  sum = wsum[0] + wsum[1] + wsum[2] + wsum[3];
  const float inv = 1.0f / sum;

  #pragma unroll
  for (int i = 0; i < 8; ++i) {
    const int s = tid + i * 256;
    out[(size_t)b * S_SZ + s] = pe[i] * inv;
  }
}

extern "C" void kernel_launch(void* const* d_in, const int* in_sizes, int n_in,
                              void* d_out, int out_size, void* d_ws, size_t ws_size,
                              hipStream_t stream) {
  const float* hidden  = (const float*)d_in[0];  // (32, 1024)
  const float* enc     = (const float*)d_in[1];  // (32, 2048, 1024)
  const int*   lengths = (const int*)d_in[2];    // (32,)
  const float* Wq      = (const float*)d_in[3];  // (1024, 1024)
  const float* Wk      = (const float*)d_in[4];  // (1024, 1024)
  const float* v       = (const float*)d_in[5];  // (1024,)
  float* out = (float*)d_out;                    // (32, 2048) fp32

  // ws layout: B16 (2 MB) | q (128 KB) | partial (2 MB)   — 4.2 MB total
  char* ws = (char*)d_ws;
  _Float16* B16     = (_Float16*)ws;
  float*    q       = (float*)(ws + 2097152);
  float*    partial = (float*)(ws + 2097152 + 131072);

  convert_f32_to_f16<<<1024, 256, 0, stream>>>(Wk, (h4*)B16, (H_SZ * H_SZ) / 4);
  query_kernel<<<128, 256, 0, stream>>>(hidden, Wq, q);
  fused_keys_kernel<<<(M_SZ / TILE) * (H_SZ / TILE), 256, 0, stream>>>(enc, B16, q, v, partial);
  softmax_kernel<<<B_SZ, 256, 0, stream>>>(partial, lengths, out);
}